// Round 3
// baseline (2626.464 us; speedup 1.0000x reference)
//
#include <hip/hip_runtime.h>
#include <hip/hip_bf16.h>
#include <stdint.h>

#define Bn 256
#define Tn 127
#define Kn 128
#define Hn 256

typedef float f32x4 __attribute__((ext_vector_type(4)));
typedef short s16x8 __attribute__((ext_vector_type(8)));

__device__ __forceinline__ float bf2f(unsigned short b){
  union { unsigned u; float f; } v; v.u = ((unsigned)b) << 16; return v.f;
}
__device__ __forceinline__ unsigned short f2bf_rn(float f){
  union { __hip_bfloat16 h; unsigned short s; } u;
  u.h = __float2bfloat16(f);
  return u.s;
}
__device__ __forceinline__ s16x8 cvt8(f32x4 a, f32x4 b){
  union { __hip_bfloat162 h2; unsigned short s[2]; } u0,u1,u2,u3;
  u0.h2 = __float22bfloat162_rn(float2{a[0],a[1]});
  u1.h2 = __float22bfloat162_rn(float2{a[2],a[3]});
  u2.h2 = __float22bfloat162_rn(float2{b[0],b[1]});
  u3.h2 = __float22bfloat162_rn(float2{b[2],b[3]});
  s16x8 r;
  r[0]=(short)u0.s[0]; r[1]=(short)u0.s[1]; r[2]=(short)u1.s[0]; r[3]=(short)u1.s[1];
  r[4]=(short)u2.s[0]; r[5]=(short)u2.s[1]; r[6]=(short)u3.s[0]; r[7]=(short)u3.s[1];
  return r;
}
__device__ __forceinline__ float sigf(float x){ return 1.f/(1.f+__expf(-x)); }
__device__ __forceinline__ float tanh_fast(float x){
  float ax = fabsf(x);
  float e = __expf(-2.f*ax);
  float t = (1.f - e)/(1.f + e);
  return x < 0.f ? -t : t;
}

// ---------------- Phase 0: alpha = softmax(x_score), weight = alpha*input -----
// 2 half-waves split the t-dimension for both the dot-product and the store.
__global__ __launch_bounds__(256) void phase0_kernel(
    const float* __restrict__ in, const float* __restrict__ fc_w,
    float* __restrict__ out)
{
  const int b    = blockIdx.x;
  const int tid  = threadIdx.x;
  const int k    = tid & 127;
  const int half = tid >> 7;
  __shared__ float wx[Tn+1];
  __shared__ float partial[2][128];
  __shared__ float red[8];
  if (tid < Tn) wx[tid] = fc_w[2*Hn + tid];
  __syncthreads();

  const float* ib = in + (size_t)b*Tn*Kn;
  const int t0 = half*64, t1 = half ? Tn : 64;
  float acc = 0.f;
  for (int t=t0; t<t1; t++) acc += ib[t*Kn + k] * wx[t];
  partial[half][k] = acc;
  __syncthreads();
  const float tot = partial[0][k] + partial[1][k];

  float mx = tot;
#pragma unroll
  for (int o=32;o>0;o>>=1) mx = fmaxf(mx, __shfl_xor(mx, o));
  const int wv = tid >> 6;
  if ((tid & 63) == 0) red[wv] = mx;
  __syncthreads();
  mx = fmaxf(fmaxf(red[0],red[1]), fmaxf(red[2],red[3]));
  float e = __expf(tot - mx);
  float sm = e;
#pragma unroll
  for (int o=32;o>0;o>>=1) sm += __shfl_xor(sm, o);
  if ((tid & 63) == 0) red[4+wv] = sm;
  __syncthreads();
  const float alpha = e / (red[4] + red[5]);   // waves 0,1 cover k=0..127

  float* ob = out + (size_t)b*Tn*Kn;
  for (int t=t0; t<t1; t++) ob[t*Kn + k] = alpha * ib[t*Kn + k];
}

// ---------------- Scan: 32 WGs x 1024 thr; one 8-batch group per WG ----------
// MFMA 16x16x32 bf16. A rows 0-7 = h_hi (batches), rows 8-15 = h_lo; the x
// tiles use rows 0-7 (rows 8-15 zero). D rows m / m+8 are hi/lo partials,
// combined with one shfl_xor(32). h state lives ONLY in LDS (double buffer);
// one __syncthreads per step; zero cross-WG traffic.
__global__ __launch_bounds__(1024) void scan_kernel(
    const float* __restrict__ W_ih, const float* __restrict__ W_hh,
    const float* __restrict__ b_ih, const float* __restrict__ b_hh,
    float* __restrict__ out)
{
  const int g    = blockIdx.x;        // 0..31
  const int b0   = g * 8;
  const int tid  = threadIdx.x;
  const int w    = tid >> 6;          // wave 0..15
  const int lane = tid & 63;
  const int c    = lane & 15;
  const int quad = lane >> 4;
  const int u    = w*16 + c;          // hidden unit 0..255

  __shared__ __align__(16) unsigned short hhi[2][8*272]; // stride 272: 0-conflict form (R2)
  __shared__ __align__(16) unsigned short hlo[2][8*272];

  // --- persistent B fragments: 4 gate tiles (i,f,g,o), K=256 (whh) / 128 (wih)
  s16x8 whh[4][8], wih[4][4];
  float bias[4];
#pragma unroll
  for (int G=0; G<4; G++){
    const int grow = G*Hn + u;
    bias[G] = b_ih[grow] + b_hh[grow];
#pragma unroll
    for (int kb=0; kb<8; kb++){
      const float* p = W_hh + (size_t)grow*Hn + kb*32 + quad*8;
      whh[G][kb] = cvt8(*(const f32x4*)p, *(const f32x4*)(p+4));
    }
#pragma unroll
    for (int kb=0; kb<4; kb++){
      const float* p = W_ih + (size_t)grow*Kn + kb*32 + quad*8;
      wih[G][kb] = cvt8(*(const f32x4*)p, *(const f32x4*)(p+4));
    }
  }

  // epilogue split: quad q handles regs rr = rsel0+rp (rp=0,1), batch m = m0+rp
  // q0: m{0,1}  q1: m{4,5}  q2: m{2,3}  q3: m{6,7}
  const int rsel0 = (quad >> 1) * 2;
  const int prr0  = rsel0 ^ 2;          // reg index to EXPORT to the partner
  const int m0    = (quad & 1)*4 + rsel0;
  float cst[2] = {0.f, 0.f};

  const size_t enc_base = (size_t)Bn*Tn*Kn;
  const float* xrow = out + (size_t)(b0 + (c & 7))*Tn*Kn;  // lanes c<8: batch c

  for (int t=0; t<Tn; t++){
    const int pb = t & 1;

    // ---- x fragment loads (lanes c<8; rows 8-15 stay zero) ----
    f32x4 xa[4], xb[4];
    if (c < 8){
      const float* xp = xrow + (size_t)t*Kn + quad*8;
#pragma unroll
      for (int kb=0; kb<4; kb++){
        xa[kb] = *(const f32x4*)(xp + kb*32);
        xb[kb] = *(const f32x4*)(xp + kb*32 + 4);
      }
    }

    f32x4 acc[4] = {{0.f,0.f,0.f,0.f},{0.f,0.f,0.f,0.f},
                    {0.f,0.f,0.f,0.f},{0.f,0.f,0.f,0.f}};

    // ---- h part: A rows = 8 hi-batches | 8 lo-batches, K=256 ----
    if (t > 0){
      const unsigned short* hb = (c < 8) ? &hhi[pb][c*272] : &hlo[pb][(c-8)*272];
#pragma unroll
      for (int kb=0; kb<8; kb++){
        const s16x8 af = *(const s16x8*)(hb + kb*32 + quad*8);
        acc[0] = __builtin_amdgcn_mfma_f32_16x16x32_bf16(af, whh[0][kb], acc[0],0,0,0);
        acc[1] = __builtin_amdgcn_mfma_f32_16x16x32_bf16(af, whh[1][kb], acc[1],0,0,0);
        acc[2] = __builtin_amdgcn_mfma_f32_16x16x32_bf16(af, whh[2][kb], acc[2],0,0,0);
        acc[3] = __builtin_amdgcn_mfma_f32_16x16x32_bf16(af, whh[3][kb], acc[3],0,0,0);
      }
    }

    // ---- x part: K=128, rows 8-15 = 0 ----
    {
      const s16x8 z = {0,0,0,0,0,0,0,0};
#pragma unroll
      for (int kb=0; kb<4; kb++){
        const s16x8 ax = (c < 8) ? cvt8(xa[kb], xb[kb]) : z;
        acc[0] = __builtin_amdgcn_mfma_f32_16x16x32_bf16(ax, wih[0][kb], acc[0],0,0,0);
        acc[1] = __builtin_amdgcn_mfma_f32_16x16x32_bf16(ax, wih[1][kb], acc[1],0,0,0);
        acc[2] = __builtin_amdgcn_mfma_f32_16x16x32_bf16(ax, wih[2][kb], acc[2],0,0,0);
        acc[3] = __builtin_amdgcn_mfma_f32_16x16x32_bf16(ax, wih[3][kb], acc[3],0,0,0);
      }
    }

    // ---- epilogue: combine hi (rows m) + lo (rows m+8) via shfl_xor(32) ----
#pragma unroll
    for (int rp=0; rp<2; rp++){
      const int rr  = rsel0 + rp;
      const int prr = prr0 + rp;
      const float gi = acc[0][rr] + __shfl_xor(acc[0][prr], 32) + bias[0];
      const float gf = acc[1][rr] + __shfl_xor(acc[1][prr], 32) + bias[1];
      const float gg = acc[2][rr] + __shfl_xor(acc[2][prr], 32) + bias[2];
      const float go = acc[3][rr] + __shfl_xor(acc[3][prr], 32) + bias[3];
      const float cn = sigf(gf)*cst[rp] + sigf(gi)*tanh_fast(gg);
      cst[rp] = cn;
      const float hn = sigf(go)*tanh_fast(cn);

      const int m = m0 + rp;
      const unsigned short hi16 = f2bf_rn(hn);
      const unsigned short lo16 = f2bf_rn(hn - bf2f(hi16));
      hhi[1-pb][m*272 + u] = hi16;
      hlo[1-pb][m*272 + u] = lo16;
      out[enc_base + ((size_t)(b0+m)*Tn + t)*Hn + u] = hn;  // fire-and-forget
    }
    __syncthreads();   // h2[1-pb] complete before step t+1 reads it
  }
}

extern "C" void kernel_launch(void* const* d_in, const int* in_sizes, int n_in,
                              void* d_out, int out_size, void* d_ws, size_t ws_size,
                              hipStream_t stream) {
  const float* input = (const float*)d_in[0];
  const float* W_ih  = (const float*)d_in[1];
  const float* W_hh  = (const float*)d_in[2];
  const float* b_ih  = (const float*)d_in[3];
  const float* b_hh  = (const float*)d_in[4];
  const float* fc_w  = (const float*)d_in[5];
  float* out = (float*)d_out;

  phase0_kernel<<<Bn, 256, 0, stream>>>(input, fc_w, out);
  scan_kernel<<<32, 1024, 0, stream>>>(W_ih, W_hh, b_ih, b_hh, out);
}